// Round 1
// baseline (196.420 us; speedup 1.0000x reference)
//
#include <hip/hip_runtime.h>
#include <math.h>

// Fused SNN: conv1d(64-tap over C) + BN + PLIF scan over T + mean + FC.
// x: (1024, 80, 500) f32.  One block per n. 384 threads = 6 waves.
// Wave w owns output channels co0 = 14*w .. co0+13 (covers 0..83, >=81 masked).
// Per t-chunk of 64 columns: stage x into zero-padded LDS rows (147 rows:
// row j holds x[j-32], rows <32 and >=112 stay zero -> no FIR boundary code),
// register-blocked FIR (14 accs, 14-reg sliding window, 64 taps unrolled),
// y tile -> LDS, then lanes 0..80 run the sequential PLIF scan in registers.

#define NTHREADS 384
#define TC       64
#define ROWS     147      // max read row = co0(70)+13+63 = 146
#define YSTRIDE  65       // +1 pad: scan column read is bank-conflict-free
#define NCHUNK   8        // 7*64 + 52 = 500

__global__ __launch_bounds__(NTHREADS, 3)
void snn_fused_kernel(const float* __restrict__ x,
                      const float* __restrict__ conv_w,
                      const float* __restrict__ conv_b,
                      const float* __restrict__ bn_gamma,
                      const float* __restrict__ bn_beta,
                      const float* __restrict__ bn_mean,
                      const float* __restrict__ bn_var,
                      const float* __restrict__ plif_w,
                      const float* __restrict__ fc_w,
                      const float* __restrict__ fc_b,
                      float* __restrict__ out)
{
    __shared__ float xs[ROWS * TC];        // 37632 B
    __shared__ float ybuf[81 * YSTRIDE];   // 21060 B
    __shared__ float wsh[64];
    __shared__ float feat[81];

    const int tid  = threadIdx.x;
    const int n    = blockIdx.x;
    const int lane = tid & 63;     // t column within chunk
    const int co0  = (tid >> 6) * 14;

    // zero the FIR padding rows once (loads only ever touch rows 32..111)
    for (int i = tid; i < 32 * TC; i += NTHREADS) xs[i] = 0.0f;
    for (int i = tid; i < 35 * TC; i += NTHREADS) xs[112 * TC + i] = 0.0f;
    if (tid < 64) wsh[tid] = conv_w[tid];

    // per-lane scan constants (lanes 0..80 = channels)
    const float decay = 1.0f / (1.0f + expf(-plif_w[0]));
    float v = 0.0f, cnt = 0.0f;
    float inv_c = 0.0f, bb_c = 0.0f;
    if (tid < 81) {
        inv_c = bn_gamma[tid] * rsqrtf(bn_var[tid] + 1e-5f);
        bb_c  = conv_b[0] * inv_c + bn_beta[tid] - bn_mean[tid] * inv_c;
    }

    const float* xn = x + (size_t)n * (80 * 500);

    __syncthreads();

    for (int chunk = 0; chunk < NCHUNK; ++chunk) {
        const int t0    = chunk * TC;
        const int tcols = (chunk == NCHUNK - 1) ? 52 : 64;   // 500 = 7*64+52
        const int f4row = tcols >> 2;                        // 16 or 13
        const int nf4   = 80 * f4row;

        // ---- stage x[n, :, t0:t0+tcols] -> xs rows 32..111 (float4) ----
        for (int i = tid; i < nf4; i += NTHREADS) {
            int c, t4;
            if (f4row == 16) { c = i >> 4; t4 = i & 15; }
            else             { c = i / 13; t4 = i - c * 13; }
            float4 vdat = *reinterpret_cast<const float4*>(xn + c * 500 + t0 + t4 * 4);
            *reinterpret_cast<float4*>(&xs[(c + 32) * TC + t4 * 4]) = vdat;
        }
        __syncthreads();

        // ---- register-blocked FIR: y[co0+r][lane], r = 0..13 ----
        {
            float acc[14];
            float win[14];
            #pragma unroll
            for (int r = 0; r < 14; ++r) acc[r] = 0.0f;
            const int base = co0 * TC + lane;
            #pragma unroll
            for (int r = 0; r < 13; ++r) win[r] = xs[base + r * TC];
            #pragma unroll
            for (int k = 0; k < 64; ++k) {
                win[(k + 13) % 14] = xs[base + (k + 13) * TC];
                const float wk = wsh[k];               // wave-uniform broadcast
                #pragma unroll
                for (int r = 0; r < 14; ++r)
                    acc[r] = fmaf(wk, win[(k + r) % 14], acc[r]);
            }
            #pragma unroll
            for (int r = 0; r < 14; ++r) {
                const int co = co0 + r;
                if (co < 81) ybuf[co * YSTRIDE + lane] = acc[r];
            }
        }
        __syncthreads();

        // ---- PLIF scan: lane c advances tcols steps ----
        if (tid < 81) {
            const float* yrow = &ybuf[tid * YSTRIDE];
            #pragma unroll 4
            for (int t = 0; t < tcols; ++t) {
                const float xt = fmaf(yrow[t], inv_c, bb_c);   // BN(conv+bias)
                v = fmaf(xt - v, decay, v);                    // v += (x-v)*decay
                const bool s = (v >= 1.0f);
                cnt += s ? 1.0f : 0.0f;
                v = s ? 0.0f : v;
            }
        }
        __syncthreads();
    }

    if (tid < 81) feat[tid] = cnt * (1.0f / 500.0f);
    __syncthreads();

    if (tid < 3) {
        float o = fc_b[tid];
        #pragma unroll 3
        for (int c = 0; c < 81; ++c)
            o = fmaf(feat[c], fc_w[tid * 81 + c], o);
        out[n * 3 + tid] = o;
    }
}

extern "C" void kernel_launch(void* const* d_in, const int* in_sizes, int n_in,
                              void* d_out, int out_size, void* d_ws, size_t ws_size,
                              hipStream_t stream)
{
    const float* x        = (const float*)d_in[0];
    const float* conv_w   = (const float*)d_in[1];
    const float* conv_b   = (const float*)d_in[2];
    const float* bn_gamma = (const float*)d_in[3];
    const float* bn_beta  = (const float*)d_in[4];
    const float* bn_mean  = (const float*)d_in[5];
    const float* bn_var   = (const float*)d_in[6];
    const float* plif_w   = (const float*)d_in[7];
    const float* fc_w     = (const float*)d_in[8];
    const float* fc_b     = (const float*)d_in[9];
    float* out            = (float*)d_out;

    snn_fused_kernel<<<1024, NTHREADS, 0, stream>>>(
        x, conv_w, conv_b, bn_gamma, bn_beta, bn_mean, bn_var,
        plif_w, fc_w, fc_b, out);
}